// Round 5
// baseline (314.299 us; speedup 1.0000x reference)
//
#include <hip/hip_runtime.h>
#include <math.h>

// B=8, L=2048, D=512, fp32 in/out. bf16 MFMA GEMMs. Column-softmax
// (axis=1 = query axis i): colsum[j]=sum_i exp(S[i,j]); j is the PV
// contraction index, so out = exp(S) @ (vp / colsum[:,None]).
// R1: qp pre-scaled by log2(e); softmax kernel uses exp2 (v_exp_f32).
// R3: LDS XOR-swizzle (col16B ^= (row>>1)&3), stage-side + read-side.
//     Bank conflicts verified 6.3M -> 0.
// R4: T3 minimum 2-phase prefetch in all GEMM K-loops: stage round t+1
//     into buf^1 BEFORE computing round t; ONE __syncthreads per round.
//     The vmcnt(0) drain at the barrier now lands after ~300cy of
//     compute instead of immediately after issue -> load latency hidden.

#define TKK 32

typedef __attribute__((ext_vector_type(8))) short bf16x8;
typedef __attribute__((ext_vector_type(4))) float floatx4;

typedef __attribute__((address_space(3))) short lds_short;
typedef const __attribute__((address_space(1))) short glob_short;

__device__ __forceinline__ short f2bf(float x) {
    unsigned u = __float_as_uint(x);
    u += 0x7fff + ((u >> 16) & 1);   // round-to-nearest-even
    return (short)(u >> 16);
}
__device__ __forceinline__ float bf2f(short s) {
    return __uint_as_float(((unsigned)(unsigned short)s) << 16);
}
__device__ __forceinline__ float exp2_fast(float x) {
    float r;
    asm("v_exp_f32 %0, %1" : "=v"(r) : "v"(x));
    return r;
}

// Stage-side swizzled column (shorts): global col unit permuted per row so
// that linear LDS rows hold XOR-swizzled data. sr = lane>>2 (row in chunk),
// unit = lane&3; swz = (row>>1)&3 = (lane>>3)&3 (chunk base is mult of 16).
#define STAGE_SC(lane) ((((lane) & 3) ^ (((lane) >> 3) & 3)) * 8)
// Read-side swizzled fragment column (shorts): h = lane>>4, row ≡ lane&15,
// s(row) = ((lane&15)>>1)&3 = (lane>>1)&3.
#define FRAG_FC(lane) (((((lane) >> 4) ^ (((lane) >> 1) & 3))) * 8)

// ---- fused prep: cast q/k/v (3*4096 blocks), cast W's (3*128), zero colsum (64)
__global__ __launch_bounds__(256) void prep(
    const float* __restrict__ q, const float* __restrict__ k,
    const float* __restrict__ v,
    const float* __restrict__ Wq, const float* __restrict__ Wk,
    const float* __restrict__ Wv,
    short* __restrict__ q_bf, short* __restrict__ k_bf, short* __restrict__ v_bf,
    short* __restrict__ Wq_bf, short* __restrict__ Wk_bf, short* __restrict__ Wv_bf,
    float* __restrict__ colsum)
{
    const int b = blockIdx.x;
    const float* in = nullptr;
    short* out = nullptr;
    long long i;
    if (b < 12288) {
        const int z = b >> 12;
        in  = (z == 0) ? q    : (z == 1) ? k    : v;
        out = (z == 0) ? q_bf : (z == 1) ? k_bf : v_bf;
        i = ((long long)(b & 4095) * 256 + threadIdx.x) * 8;
    } else if (b < 12672) {
        const int z = (b - 12288) >> 7;
        in  = (z == 0) ? Wq    : (z == 1) ? Wk    : Wv;
        out = (z == 0) ? Wq_bf : (z == 1) ? Wk_bf : Wv_bf;
        i = ((long long)((b - 12288) & 127) * 256 + threadIdx.x) * 8;
    } else {
        colsum[(b - 12672) * 256 + threadIdx.x] = 0.f;
        return;
    }
    float4 x = *(const float4*)(in + i);
    float4 y = *(const float4*)(in + i + 4);
    bf16x8 r;
    r[0] = f2bf(x.x); r[1] = f2bf(x.y); r[2] = f2bf(x.z); r[3] = f2bf(x.w);
    r[4] = f2bf(y.x); r[5] = f2bf(y.y); r[6] = f2bf(y.z); r[7] = f2bf(y.w);
    *(bf16x8*)(out + i) = r;
}

// ---------------- generic NT MFMA gemm body (2-phase prefetch) ----------------
// C[m,n] = (sum_k A[m,k]*B[n,k] + bias[n]) * escale; A:[M][K], B:[N][K] bf16.
template<int TMp, int TNp, int WM, int WN, int HAS_BIAS, int OUT_BF16>
__device__ __forceinline__ void gemm_body(
    const short* __restrict__ A, const short* __restrict__ B,
    const float* __restrict__ bias, void* __restrict__ C,
    int N, int K, int m0, int n0, float escale)
{
    __shared__ short As[2][TMp * TKK];
    __shared__ short Bs[2][TNp * TKK];
    constexpr int MI = TMp / (16 * WM);
    constexpr int NJ = TNp / (16 * WN);
    const int t    = threadIdx.x;
    const int wave = t >> 6;
    const int lane = t & 63;
    const int wm = (wave / WN) * (TMp / WM);
    const int wn = (wave % WN) * (TNp / WN);
    const int sr = lane >> 2;
    const int sc = STAGE_SC(lane);
    const int fc = FRAG_FC(lane);

    auto stage = [&](int buf, int k0) {
        #pragma unroll
        for (int c = wave; c < TMp / 16; c += 4)
            __builtin_amdgcn_global_load_lds(
                (glob_short*)(A + (long long)(m0 + c * 16 + sr) * K + k0 + sc),
                (lds_short*)(As[buf] + c * 512), 16, 0, 0);
        #pragma unroll
        for (int c = wave; c < TNp / 16; c += 4)
            __builtin_amdgcn_global_load_lds(
                (glob_short*)(B + (long long)(n0 + c * 16 + sr) * K + k0 + sc),
                (lds_short*)(Bs[buf] + c * 512), 16, 0, 0);
    };

    floatx4 acc[MI][NJ];
    #pragma unroll
    for (int i = 0; i < MI; ++i)
        #pragma unroll
        for (int j = 0; j < NJ; ++j)
            acc[i][j] = (floatx4){0.f, 0.f, 0.f, 0.f};

    const int NT = K / TKK;
    stage(0, 0);
    __syncthreads();
    int cur = 0;
    for (int tt = 0; tt < NT; ++tt) {
        if (tt + 1 < NT) stage(cur ^ 1, (tt + 1) * TKK);
        bf16x8 af[MI], bfr[NJ];
        #pragma unroll
        for (int i = 0; i < MI; ++i)
            af[i] = *(const bf16x8*)&As[cur][(wm + i * 16 + (lane & 15)) * TKK + fc];
        #pragma unroll
        for (int j = 0; j < NJ; ++j)
            bfr[j] = *(const bf16x8*)&Bs[cur][(wn + j * 16 + (lane & 15)) * TKK + fc];
        #pragma unroll
        for (int i = 0; i < MI; ++i)
            #pragma unroll
            for (int j = 0; j < NJ; ++j)
                acc[i][j] = __builtin_amdgcn_mfma_f32_16x16x32_bf16(af[i], bfr[j], acc[i][j], 0, 0, 0);
        __syncthreads();
        cur ^= 1;
    }

    // Epilogue: C/D layout col=lane&15, row=(lane>>4)*4+reg (m89-verified)
    #pragma unroll
    for (int i = 0; i < MI; ++i) {
        const int rbase = m0 + wm + i * 16 + (lane >> 4) * 4;
        #pragma unroll
        for (int j = 0; j < NJ; ++j) {
            const int col = n0 + wn + j * 16 + (lane & 15);
            const float bb = HAS_BIAS ? bias[col] : 0.f;
            #pragma unroll
            for (int r = 0; r < 4; ++r) {
                const long long off = (long long)(rbase + r) * N + col;
                const float vvv = (acc[i][j][r] + bb) * escale;
                if (OUT_BF16) ((short*)C)[off] = f2bf(vvv);
                else          ((float*)C)[off] = vvv;
            }
        }
    }
}

// ---- fused projections: z in {0,1,2} selects (x, W, bias, out) ----
// z==0 (qp) is scaled by log2(e) so the S kernel can use exp2 directly.
__global__ __launch_bounds__(256) void proj_gemm(
    const short* __restrict__ x0, const short* __restrict__ x1, const short* __restrict__ x2,
    const short* __restrict__ w0, const short* __restrict__ w1, const short* __restrict__ w2,
    const float* __restrict__ b0, const float* __restrict__ b1, const float* __restrict__ b2,
    short* __restrict__ y0, short* __restrict__ y1, short* __restrict__ y2,
    int N, int K)
{
    const int z = blockIdx.z;
    const short* A    = (z == 0) ? x0 : (z == 1) ? x1 : x2;
    const short* B    = (z == 0) ? w0 : (z == 1) ? w1 : w2;
    const float* bias = (z == 0) ? b0 : (z == 1) ? b1 : b2;
    short*       C    = (z == 0) ? y0 : (z == 1) ? y1 : y2;
    const float esc   = (z == 0) ? 1.4426950408889634f : 1.0f;
    gemm_body<128, 128, 2, 2, 1, 1>(A, B, bias, C, N, K,
                                    blockIdx.x * 128, blockIdx.y * 128, esc);
}

// ---- PV gemm: out = E @ vpT^T ----
// 128x64 tile; R4: K=32 per round, double-buffered cross-round prefetch,
// one barrier per round. LDS unchanged at 24 KB.
__global__ __launch_bounds__(256) void pv_gemm(
    const short* __restrict__ Eg, const short* __restrict__ vpTg,
    float* __restrict__ outg, int N, int K,
    long long sA, long long sB, long long sC)
{
    __shared__ short As[2][128 * TKK];
    __shared__ short Bs[2][64 * TKK];
    const int bz = blockIdx.z;
    const short* A = Eg   + (long long)bz * sA;
    const short* B = vpTg + (long long)bz * sB;
    float*       C = outg + (long long)bz * sC;

    const int m0 = blockIdx.x * 128;
    const int n0 = blockIdx.y * 64;
    const int t    = threadIdx.x;
    const int wave = t >> 6;
    const int lane = t & 63;
    const int wm = (wave >> 1) * 64;   // waves 2x2: 64-row halves
    const int wn = (wave & 1)  * 32;   // 32-col halves
    const int sr = lane >> 2;
    const int sc = STAGE_SC(lane);
    const int fc = FRAG_FC(lane);

    auto stage = [&](int buf, int kk) {
        // A: 8 chunks of 16 rows, 2 per wave; B: 4 chunks, 1 per wave
        #pragma unroll
        for (int c = wave; c < 8; c += 4)
            __builtin_amdgcn_global_load_lds(
                (glob_short*)(A + (long long)(m0 + c * 16 + sr) * K + kk + sc),
                (lds_short*)(As[buf] + c * 512), 16, 0, 0);
        __builtin_amdgcn_global_load_lds(
            (glob_short*)(B + (long long)(n0 + wave * 16 + sr) * K + kk + sc),
            (lds_short*)(Bs[buf] + wave * 512), 16, 0, 0);
    };

    floatx4 acc[4][2];
    #pragma unroll
    for (int i = 0; i < 4; ++i)
        #pragma unroll
        for (int j = 0; j < 2; ++j)
            acc[i][j] = (floatx4){0.f, 0.f, 0.f, 0.f};

    const int NT = K / TKK;   // 64
    stage(0, 0);
    __syncthreads();
    int cur = 0;
    for (int tt = 0; tt < NT; ++tt) {
        if (tt + 1 < NT) stage(cur ^ 1, (tt + 1) * TKK);
        bf16x8 af[4], bfr[2];
        #pragma unroll
        for (int i = 0; i < 4; ++i)
            af[i] = *(const bf16x8*)&As[cur][(wm + i * 16 + (lane & 15)) * TKK + fc];
        #pragma unroll
        for (int j = 0; j < 2; ++j)
            bfr[j] = *(const bf16x8*)&Bs[cur][(wn + j * 16 + (lane & 15)) * TKK + fc];
        #pragma unroll
        for (int i = 0; i < 4; ++i)
            #pragma unroll
            for (int j = 0; j < 2; ++j)
                acc[i][j] = __builtin_amdgcn_mfma_f32_16x16x32_bf16(af[i], bfr[j], acc[i][j], 0, 0, 0);
        __syncthreads();
        cur ^= 1;
    }

    #pragma unroll
    for (int i = 0; i < 4; ++i) {
        const int rbase = m0 + wm + i * 16 + (lane >> 4) * 4;
        #pragma unroll
        for (int j = 0; j < 2; ++j) {
            const int col = n0 + wn + j * 16 + (lane & 15);
            #pragma unroll
            for (int r = 0; r < 4; ++r)
                C[(long long)(rbase + r) * N + col] = acc[i][j][r];
        }
    }
}

// ---- NT MFMA gemm with fused exp2 + column-sum: E = exp2(A@B^T) bf16,
//      colsum[n] += sum_m exp2(...)   (128x128 tile, waves 2x2)
// R4: K=32 per round, cross-round prefetch, one barrier per round.
__global__ __launch_bounds__(256) void gemm_nt_exp_colsum(
    const short* __restrict__ A, const short* __restrict__ B,
    short* __restrict__ E, float* __restrict__ colsum,
    int N, int K, long long sA, long long sB, long long sE)
{
    __shared__ short As[2][128 * TKK];
    __shared__ short Bs[2][128 * TKK];
    __shared__ float wsum[4][64];
    const int bz = blockIdx.z;
    A += (long long)bz * sA;
    B += (long long)bz * sB;
    E += (long long)bz * sE;
    colsum += (long long)bz * N;

    const int m0 = blockIdx.x * 128;
    const int n0 = blockIdx.y * 128;
    const int t    = threadIdx.x;
    const int wave = t >> 6;
    const int lane = t & 63;
    const int wm = (wave >> 1) * 64;
    const int wn = (wave & 1)  * 64;
    const int sr = lane >> 2;
    const int sc = STAGE_SC(lane);
    const int fc = FRAG_FC(lane);

    auto stage = [&](int buf, int kk) {
        #pragma unroll
        for (int it = 0; it < 2; ++it) {
            const int chunk = it * 4 + wave;
            const int r = chunk * 16 + sr;
            __builtin_amdgcn_global_load_lds(
                (glob_short*)(A + (long long)(m0 + r) * K + kk + sc),
                (lds_short*)(As[buf] + chunk * 512), 16, 0, 0);
            __builtin_amdgcn_global_load_lds(
                (glob_short*)(B + (long long)(n0 + r) * K + kk + sc),
                (lds_short*)(Bs[buf] + chunk * 512), 16, 0, 0);
        }
    };

    floatx4 acc[4][4];
    #pragma unroll
    for (int i = 0; i < 4; ++i)
        #pragma unroll
        for (int j = 0; j < 4; ++j)
            acc[i][j] = (floatx4){0.f, 0.f, 0.f, 0.f};

    const int NT = K / TKK;   // 16
    stage(0, 0);
    __syncthreads();
    int cur = 0;
    for (int tt = 0; tt < NT; ++tt) {
        if (tt + 1 < NT) stage(cur ^ 1, (tt + 1) * TKK);
        bf16x8 af[4], bfr[4];
        #pragma unroll
        for (int i = 0; i < 4; ++i)
            af[i] = *(const bf16x8*)&As[cur][(wm + i * 16 + (lane & 15)) * TKK + fc];
        #pragma unroll
        for (int j = 0; j < 4; ++j)
            bfr[j] = *(const bf16x8*)&Bs[cur][(wn + j * 16 + (lane & 15)) * TKK + fc];
        #pragma unroll
        for (int i = 0; i < 4; ++i)
            #pragma unroll
            for (int j = 0; j < 4; ++j)
                acc[i][j] = __builtin_amdgcn_mfma_f32_16x16x32_bf16(af[i], bfr[j], acc[i][j], 0, 0, 0);
        __syncthreads();
        cur ^= 1;
    }

    float csum[4] = {0.f, 0.f, 0.f, 0.f};
    #pragma unroll
    for (int i = 0; i < 4; ++i) {
        const int rbase = wm + i * 16 + (lane >> 4) * 4;
        #pragma unroll
        for (int j = 0; j < 4; ++j) {
            const int col = wn + j * 16 + (lane & 15);
            #pragma unroll
            for (int r = 0; r < 4; ++r) {
                const float e = exp2_fast(acc[i][j][r]);
                E[(long long)(m0 + rbase + r) * N + (n0 + col)] = f2bf(e);
                csum[j] += e;
            }
        }
    }
    #pragma unroll
    for (int j = 0; j < 4; ++j) {
        csum[j] += __shfl_xor(csum[j], 16);
        csum[j] += __shfl_xor(csum[j], 32);
    }
    if (lane < 16) {
        #pragma unroll
        for (int j = 0; j < 4; ++j)
            wsum[wave][j * 16 + lane] = csum[j];
    }
    __syncthreads();
    if (t < 128) {
        const float s = (t < 64) ? (wsum[0][t] + wsum[2][t])
                                 : (wsum[1][t - 64] + wsum[3][t - 64]);
        atomicAdd(&colsum[n0 + t], s);
    }
}

// ---- bf16 transpose + per-row scale: out[c][r] = in[r][c] / colsum[r] ----
__global__ __launch_bounds__(256) void transpose_scale_bf16(
    const short* __restrict__ in, const float* __restrict__ colsum,
    short* __restrict__ out, int R, int Cc)
{
    __shared__ short tile[32][33];
    const int b = blockIdx.z;
    in  += (long long)b * R * Cc;
    out += (long long)b * R * Cc;
    colsum += (long long)b * R;
    const int c0 = blockIdx.x * 32, r0 = blockIdx.y * 32;
    const int tx = threadIdx.x & 31, ty = threadIdx.x >> 5;
    #pragma unroll
    for (int rr = ty; rr < 32; rr += 8) {
        const float rs = 1.f / colsum[r0 + rr];
        tile[rr][tx] = f2bf(bf2f(in[(long long)(r0 + rr) * Cc + c0 + tx]) * rs);
    }
    __syncthreads();
    #pragma unroll
    for (int rr = ty; rr < 32; rr += 8)
        out[(long long)(c0 + rr) * R + r0 + tx] = tile[tx][rr];
}

extern "C" void kernel_launch(void* const* d_in, const int* in_sizes, int n_in,
                              void* d_out, int out_size, void* d_ws, size_t ws_size,
                              hipStream_t stream) {
    const float* q  = (const float*)d_in[0];
    const float* k  = (const float*)d_in[1];
    const float* v  = (const float*)d_in[2];
    const float* Wq = (const float*)d_in[3];
    const float* bq = (const float*)d_in[4];
    const float* Wk = (const float*)d_in[5];
    const float* bk = (const float*)d_in[6];
    const float* Wv = (const float*)d_in[7];
    const float* bv = (const float*)d_in[8];
    float* out = (float*)d_out;

    const int Bb = 8, L = 2048, D = 512;
    const long long BLD = (long long)Bb * L * D;   // 8,388,608
    const long long BLL = (long long)Bb * L * L;   // 33,554,432
    const long long DD  = (long long)D * D;

    // ---- workspace layout (shorts unless noted) ----
    short* base  = (short*)d_ws;
    short* q_bf  = base;                 // BLD
    short* k_bf  = q_bf  + BLD;         // BLD
    short* v_bf  = k_bf  + BLD;         // BLD
    short* qp_bf = v_bf  + BLD;         // BLD
    short* kp_bf = qp_bf + BLD;         // BLD
    short* vp_bf = kp_bf + BLD;         // BLD
    short* vpT   = vp_bf + BLD;         // BLD
    short* Wq_bf = vpT   + BLD;         // DD
    short* Wk_bf = Wq_bf + DD;          // DD
    short* Wv_bf = Wk_bf + DD;          // DD
    short* E_bf  = Wv_bf + DD;          // BLL shorts
    float* colsum = (float*)(E_bf + BLL); // B*L floats

    dim3 blk(256);

    // 1) fused casts + colsum zero (12736 blocks)
    prep<<<dim3(12736), blk, 0, stream>>>(q, k, v, Wq, Wk, Wv,
                                          q_bf, k_bf, v_bf,
                                          Wq_bf, Wk_bf, Wv_bf, colsum);

    // 2) fused projections: M=B*L=16384, N=D=512, K=D=512, out bf16
    dim3 gproj((Bb * L) / 128, D / 128, 3);
    proj_gemm<<<gproj, blk, 0, stream>>>(q_bf, k_bf, v_bf,
                                         Wq_bf, Wk_bf, Wv_bf,
                                         bq, bk, bv,
                                         qp_bf, kp_bf, vp_bf, D, D);

    // 3) E = exp2(qp @ kp^T), colsum[b,j] = sum_i E[b,i,j]   (M=N=L, K=D)
    dim3 gS(L / 128, L / 128, Bb);
    gemm_nt_exp_colsum<<<gS, blk, 0, stream>>>(qp_bf, kp_bf, E_bf, colsum,
                                               L, D,
                                               (long long)L * D, (long long)L * D,
                                               (long long)L * L);

    // 4) vpT[d][j] = vp[j][d] / colsum[j]  per batch
    dim3 gT(D / 32, L / 32, Bb);
    transpose_scale_bf16<<<gT, blk, 0, stream>>>(vp_bf, colsum, vpT, L, D);

    // 5) out = E @ vpT^T : M=L (128-tiles), N=D (64-tiles), K=L
    dim3 gO(L / 128, D / 64, Bb);
    pv_gemm<<<gO, blk, 0, stream>>>(E_bf, vpT, out, D, L,
                                    (long long)L * L, (long long)D * L,
                                    (long long)L * D);
}

// Round 6
// 307.276 us; speedup vs baseline: 1.0229x; 1.0229x over previous
//
#include <hip/hip_runtime.h>
#include <math.h>

// B=8, L=2048, D=512, fp32 in/out. bf16 MFMA GEMMs. Column-softmax
// (axis=1 = query axis i): colsum[j]=sum_i exp(S[i,j]); j is the PV
// contraction index, so out = exp(S) @ (vp / colsum[:,None]).
// R1: qp pre-scaled by log2(e); softmax kernel uses exp2 (v_exp_f32).
// R3: LDS XOR-swizzle (col16B ^= (row>>1)&3), stage-side + read-side.
//     Bank conflicts verified 6.3M -> 0.
// R4 LESSON (regression): prefetch with 32-K rounds DOUBLES the number of
//     vmcnt(0) barrier drains; each drain still exposes (latency-200cy).
// R5: pv only: 64-K rounds + cross-round prefetch (buf[2] of full 64-K),
//     ONE barrier per 64-K. Same drain count as R3, but loads now issued
//     a full 32-MFMA compute window (~450cy) before the drain.
//     proj/S reverted to exact R3 structure.

#define TKK 32

typedef __attribute__((ext_vector_type(8))) short bf16x8;
typedef __attribute__((ext_vector_type(4))) float floatx4;

typedef __attribute__((address_space(3))) short lds_short;
typedef const __attribute__((address_space(1))) short glob_short;

__device__ __forceinline__ short f2bf(float x) {
    unsigned u = __float_as_uint(x);
    u += 0x7fff + ((u >> 16) & 1);   // round-to-nearest-even
    return (short)(u >> 16);
}
__device__ __forceinline__ float bf2f(short s) {
    return __uint_as_float(((unsigned)(unsigned short)s) << 16);
}
__device__ __forceinline__ float exp2_fast(float x) {
    float r;
    asm("v_exp_f32 %0, %1" : "=v"(r) : "v"(x));
    return r;
}

// Stage-side swizzled column (shorts): global col unit permuted per row so
// that linear LDS rows hold XOR-swizzled data. sr = lane>>2 (row in chunk),
// unit = lane&3; swz = (row>>1)&3 = (lane>>3)&3 (chunk base is mult of 16).
#define STAGE_SC(lane) ((((lane) & 3) ^ (((lane) >> 3) & 3)) * 8)
// Read-side swizzled fragment column (shorts): h = lane>>4, row ≡ lane&15,
// s(row) = ((lane&15)>>1)&3 = (lane>>1)&3.
#define FRAG_FC(lane) (((((lane) >> 4) ^ (((lane) >> 1) & 3))) * 8)

// ---- fused prep: cast q/k/v (3*4096 blocks), cast W's (3*128), zero colsum (64)
__global__ __launch_bounds__(256) void prep(
    const float* __restrict__ q, const float* __restrict__ k,
    const float* __restrict__ v,
    const float* __restrict__ Wq, const float* __restrict__ Wk,
    const float* __restrict__ Wv,
    short* __restrict__ q_bf, short* __restrict__ k_bf, short* __restrict__ v_bf,
    short* __restrict__ Wq_bf, short* __restrict__ Wk_bf, short* __restrict__ Wv_bf,
    float* __restrict__ colsum)
{
    const int b = blockIdx.x;
    const float* in = nullptr;
    short* out = nullptr;
    long long i;
    if (b < 12288) {
        const int z = b >> 12;
        in  = (z == 0) ? q    : (z == 1) ? k    : v;
        out = (z == 0) ? q_bf : (z == 1) ? k_bf : v_bf;
        i = ((long long)(b & 4095) * 256 + threadIdx.x) * 8;
    } else if (b < 12672) {
        const int z = (b - 12288) >> 7;
        in  = (z == 0) ? Wq    : (z == 1) ? Wk    : Wv;
        out = (z == 0) ? Wq_bf : (z == 1) ? Wk_bf : Wv_bf;
        i = ((long long)((b - 12288) & 127) * 256 + threadIdx.x) * 8;
    } else {
        colsum[(b - 12672) * 256 + threadIdx.x] = 0.f;
        return;
    }
    float4 x = *(const float4*)(in + i);
    float4 y = *(const float4*)(in + i + 4);
    bf16x8 r;
    r[0] = f2bf(x.x); r[1] = f2bf(x.y); r[2] = f2bf(x.z); r[3] = f2bf(x.w);
    r[4] = f2bf(y.x); r[5] = f2bf(y.y); r[6] = f2bf(y.z); r[7] = f2bf(y.w);
    *(bf16x8*)(out + i) = r;
}

// ---------------- generic NT MFMA gemm body (R3 structure) ----------------
// C[m,n] = (sum_k A[m,k]*B[n,k] + bias[n]) * escale; A:[M][K], B:[N][K] bf16.
template<int TMp, int TNp, int WM, int WN, int HAS_BIAS, int OUT_BF16>
__device__ __forceinline__ void gemm_body(
    const short* __restrict__ A, const short* __restrict__ B,
    const float* __restrict__ bias, void* __restrict__ C,
    int N, int K, int m0, int n0, float escale)
{
    __shared__ short As[TMp * TKK];
    __shared__ short Bs[TNp * TKK];
    constexpr int MI = TMp / (16 * WM);
    constexpr int NJ = TNp / (16 * WN);
    const int t    = threadIdx.x;
    const int wave = t >> 6;
    const int lane = t & 63;
    const int wm = (wave / WN) * (TMp / WM);
    const int wn = (wave % WN) * (TNp / WN);
    const int sr = lane >> 2;
    const int sc = STAGE_SC(lane);
    const int fc = FRAG_FC(lane);

    floatx4 acc[MI][NJ];
    #pragma unroll
    for (int i = 0; i < MI; ++i)
        #pragma unroll
        for (int j = 0; j < NJ; ++j)
            acc[i][j] = (floatx4){0.f, 0.f, 0.f, 0.f};

    for (int k0 = 0; k0 < K; k0 += TKK) {
        #pragma unroll
        for (int c = wave; c < TMp / 16; c += 4)
            __builtin_amdgcn_global_load_lds(
                (glob_short*)(A + (long long)(m0 + c * 16 + sr) * K + k0 + sc),
                (lds_short*)(As + c * 512), 16, 0, 0);
        #pragma unroll
        for (int c = wave; c < TNp / 16; c += 4)
            __builtin_amdgcn_global_load_lds(
                (glob_short*)(B + (long long)(n0 + c * 16 + sr) * K + k0 + sc),
                (lds_short*)(Bs + c * 512), 16, 0, 0);
        __syncthreads();
        bf16x8 af[MI], bfr[NJ];
        #pragma unroll
        for (int i = 0; i < MI; ++i)
            af[i] = *(const bf16x8*)&As[(wm + i * 16 + (lane & 15)) * TKK + fc];
        #pragma unroll
        for (int j = 0; j < NJ; ++j)
            bfr[j] = *(const bf16x8*)&Bs[(wn + j * 16 + (lane & 15)) * TKK + fc];
        #pragma unroll
        for (int i = 0; i < MI; ++i)
            #pragma unroll
            for (int j = 0; j < NJ; ++j)
                acc[i][j] = __builtin_amdgcn_mfma_f32_16x16x32_bf16(af[i], bfr[j], acc[i][j], 0, 0, 0);
        __syncthreads();
    }

    // Epilogue: C/D layout col=lane&15, row=(lane>>4)*4+reg (m89-verified)
    #pragma unroll
    for (int i = 0; i < MI; ++i) {
        const int rbase = m0 + wm + i * 16 + (lane >> 4) * 4;
        #pragma unroll
        for (int j = 0; j < NJ; ++j) {
            const int col = n0 + wn + j * 16 + (lane & 15);
            const float bb = HAS_BIAS ? bias[col] : 0.f;
            #pragma unroll
            for (int r = 0; r < 4; ++r) {
                const long long off = (long long)(rbase + r) * N + col;
                const float vvv = (acc[i][j][r] + bb) * escale;
                if (OUT_BF16) ((short*)C)[off] = f2bf(vvv);
                else          ((float*)C)[off] = vvv;
            }
        }
    }
}

// ---- fused projections: z in {0,1,2} selects (x, W, bias, out) ----
// z==0 (qp) is scaled by log2(e) so the S kernel can use exp2 directly.
__global__ __launch_bounds__(256) void proj_gemm(
    const short* __restrict__ x0, const short* __restrict__ x1, const short* __restrict__ x2,
    const short* __restrict__ w0, const short* __restrict__ w1, const short* __restrict__ w2,
    const float* __restrict__ b0, const float* __restrict__ b1, const float* __restrict__ b2,
    short* __restrict__ y0, short* __restrict__ y1, short* __restrict__ y2,
    int N, int K)
{
    const int z = blockIdx.z;
    const short* A    = (z == 0) ? x0 : (z == 1) ? x1 : x2;
    const short* B    = (z == 0) ? w0 : (z == 1) ? w1 : w2;
    const float* bias = (z == 0) ? b0 : (z == 1) ? b1 : b2;
    short*       C    = (z == 0) ? y0 : (z == 1) ? y1 : y2;
    const float esc   = (z == 0) ? 1.4426950408889634f : 1.0f;
    gemm_body<128, 128, 2, 2, 1, 1>(A, B, bias, C, N, K,
                                    blockIdx.x * 128, blockIdx.y * 128, esc);
}

// ---- PV gemm: out = E @ vpT^T ----
// R5: 128x64 tile; 64-K rounds, cross-round double-buffer prefetch,
// ONE barrier per 64-K round. LDS 48 KB -> 3 blocks/CU.
__global__ __launch_bounds__(256) void pv_gemm(
    const short* __restrict__ Eg, const short* __restrict__ vpTg,
    float* __restrict__ outg, int N, int K,
    long long sA, long long sB, long long sC)
{
    __shared__ short As[2][2][128 * TKK];   // [buf][half][chunk*512...]
    __shared__ short Bs[2][2][64 * TKK];
    const int bz = blockIdx.z;
    const short* A = Eg   + (long long)bz * sA;
    const short* B = vpTg + (long long)bz * sB;
    float*       C = outg + (long long)bz * sC;

    const int m0 = blockIdx.x * 128;
    const int n0 = blockIdx.y * 64;
    const int t    = threadIdx.x;
    const int wave = t >> 6;
    const int lane = t & 63;
    const int wm = (wave >> 1) * 64;   // waves 2x2: 64-row halves
    const int wn = (wave & 1)  * 32;   // 32-col halves
    const int sr = lane >> 2;
    const int sc = STAGE_SC(lane);
    const int fc = FRAG_FC(lane);

    auto stage = [&](int buf, int k0) {
        #pragma unroll
        for (int h = 0; h < 2; ++h) {
            const int kk = k0 + h * TKK;
            // A: 8 chunks of 16 rows, 2 per wave; B: 4 chunks, 1 per wave
            #pragma unroll
            for (int c = wave; c < 8; c += 4)
                __builtin_amdgcn_global_load_lds(
                    (glob_short*)(A + (long long)(m0 + c * 16 + sr) * K + kk + sc),
                    (lds_short*)(As[buf][h] + c * 512), 16, 0, 0);
            __builtin_amdgcn_global_load_lds(
                (glob_short*)(B + (long long)(n0 + wave * 16 + sr) * K + kk + sc),
                (lds_short*)(Bs[buf][h] + wave * 512), 16, 0, 0);
        }
    };

    floatx4 acc[4][2];
    #pragma unroll
    for (int i = 0; i < 4; ++i)
        #pragma unroll
        for (int j = 0; j < 2; ++j)
            acc[i][j] = (floatx4){0.f, 0.f, 0.f, 0.f};

    const int NT = K / (2 * TKK);   // 32 rounds of 64-K
    stage(0, 0);
    __syncthreads();
    int cur = 0;
    for (int tt = 0; tt < NT; ++tt) {
        if (tt + 1 < NT) stage(cur ^ 1, (tt + 1) * 2 * TKK);
        #pragma unroll
        for (int h = 0; h < 2; ++h) {
            bf16x8 af[4], bfr[2];
            #pragma unroll
            for (int i = 0; i < 4; ++i)
                af[i] = *(const bf16x8*)&As[cur][h][(wm + i * 16 + (lane & 15)) * TKK + fc];
            #pragma unroll
            for (int j = 0; j < 2; ++j)
                bfr[j] = *(const bf16x8*)&Bs[cur][h][(wn + j * 16 + (lane & 15)) * TKK + fc];
            #pragma unroll
            for (int i = 0; i < 4; ++i)
                #pragma unroll
                for (int j = 0; j < 2; ++j)
                    acc[i][j] = __builtin_amdgcn_mfma_f32_16x16x32_bf16(af[i], bfr[j], acc[i][j], 0, 0, 0);
        }
        __syncthreads();
        cur ^= 1;
    }

    #pragma unroll
    for (int i = 0; i < 4; ++i) {
        const int rbase = m0 + wm + i * 16 + (lane >> 4) * 4;
        #pragma unroll
        for (int j = 0; j < 2; ++j) {
            const int col = n0 + wn + j * 16 + (lane & 15);
            #pragma unroll
            for (int r = 0; r < 4; ++r)
                C[(long long)(rbase + r) * N + col] = acc[i][j][r];
        }
    }
}

// ---- NT MFMA gemm with fused exp2 + column-sum: E = exp2(A@B^T) bf16,
//      colsum[n] += sum_m exp2(...)   (128x128 tile, waves 2x2)
// R3 structure: 2 K-blocks per barrier round (8 rounds), exp2 epilogue.
__global__ __launch_bounds__(256) void gemm_nt_exp_colsum(
    const short* __restrict__ A, const short* __restrict__ B,
    short* __restrict__ E, float* __restrict__ colsum,
    int N, int K, long long sA, long long sB, long long sE)
{
    __shared__ short As[2][128 * TKK];
    __shared__ short Bs[2][128 * TKK];
    __shared__ float wsum[4][64];
    const int bz = blockIdx.z;
    A += (long long)bz * sA;
    B += (long long)bz * sB;
    E += (long long)bz * sE;
    colsum += (long long)bz * N;

    const int m0 = blockIdx.x * 128;
    const int n0 = blockIdx.y * 128;
    const int t    = threadIdx.x;
    const int wave = t >> 6;
    const int lane = t & 63;
    const int wm = (wave >> 1) * 64;
    const int wn = (wave & 1)  * 64;
    const int sr = lane >> 2;
    const int sc = STAGE_SC(lane);
    const int fc = FRAG_FC(lane);

    floatx4 acc[4][4];
    #pragma unroll
    for (int i = 0; i < 4; ++i)
        #pragma unroll
        for (int j = 0; j < 4; ++j)
            acc[i][j] = (floatx4){0.f, 0.f, 0.f, 0.f};

    for (int k0 = 0; k0 < K; k0 += 2 * TKK) {
        #pragma unroll
        for (int h = 0; h < 2; ++h) {
            const int kk = k0 + h * TKK;
            #pragma unroll
            for (int it = 0; it < 2; ++it) {
                const int chunk = it * 4 + wave;
                const int r = chunk * 16 + sr;
                __builtin_amdgcn_global_load_lds(
                    (glob_short*)(A + (long long)(m0 + r) * K + kk + sc),
                    (lds_short*)(As[h] + chunk * 512), 16, 0, 0);
                __builtin_amdgcn_global_load_lds(
                    (glob_short*)(B + (long long)(n0 + r) * K + kk + sc),
                    (lds_short*)(Bs[h] + chunk * 512), 16, 0, 0);
            }
        }
        __syncthreads();
        #pragma unroll
        for (int h = 0; h < 2; ++h) {
            bf16x8 af[4], bfr[4];
            #pragma unroll
            for (int i = 0; i < 4; ++i)
                af[i] = *(const bf16x8*)&As[h][(wm + i * 16 + (lane & 15)) * TKK + fc];
            #pragma unroll
            for (int j = 0; j < 4; ++j)
                bfr[j] = *(const bf16x8*)&Bs[h][(wn + j * 16 + (lane & 15)) * TKK + fc];
            #pragma unroll
            for (int i = 0; i < 4; ++i)
                #pragma unroll
                for (int j = 0; j < 4; ++j)
                    acc[i][j] = __builtin_amdgcn_mfma_f32_16x16x32_bf16(af[i], bfr[j], acc[i][j], 0, 0, 0);
        }
        __syncthreads();
    }

    float csum[4] = {0.f, 0.f, 0.f, 0.f};
    #pragma unroll
    for (int i = 0; i < 4; ++i) {
        const int rbase = wm + i * 16 + (lane >> 4) * 4;
        #pragma unroll
        for (int j = 0; j < 4; ++j) {
            const int col = wn + j * 16 + (lane & 15);
            #pragma unroll
            for (int r = 0; r < 4; ++r) {
                const float e = exp2_fast(acc[i][j][r]);
                E[(long long)(m0 + rbase + r) * N + (n0 + col)] = f2bf(e);
                csum[j] += e;
            }
        }
    }
    #pragma unroll
    for (int j = 0; j < 4; ++j) {
        csum[j] += __shfl_xor(csum[j], 16);
        csum[j] += __shfl_xor(csum[j], 32);
    }
    if (lane < 16) {
        #pragma unroll
        for (int j = 0; j < 4; ++j)
            wsum[wave][j * 16 + lane] = csum[j];
    }
    __syncthreads();
    if (t < 128) {
        const float s = (t < 64) ? (wsum[0][t] + wsum[2][t])
                                 : (wsum[1][t - 64] + wsum[3][t - 64]);
        atomicAdd(&colsum[n0 + t], s);
    }
}

// ---- bf16 transpose + per-row scale: out[c][r] = in[r][c] / colsum[r] ----
__global__ __launch_bounds__(256) void transpose_scale_bf16(
    const short* __restrict__ in, const float* __restrict__ colsum,
    short* __restrict__ out, int R, int Cc)
{
    __shared__ short tile[32][33];
    const int b = blockIdx.z;
    in  += (long long)b * R * Cc;
    out += (long long)b * R * Cc;
    colsum += (long long)b * R;
    const int c0 = blockIdx.x * 32, r0 = blockIdx.y * 32;
    const int tx = threadIdx.x & 31, ty = threadIdx.x >> 5;
    #pragma unroll
    for (int rr = ty; rr < 32; rr += 8) {
        const float rs = 1.f / colsum[r0 + rr];
        tile[rr][tx] = f2bf(bf2f(in[(long long)(r0 + rr) * Cc + c0 + tx]) * rs);
    }
    __syncthreads();
    #pragma unroll
    for (int rr = ty; rr < 32; rr += 8)
        out[(long long)(c0 + rr) * R + r0 + tx] = tile[tx][rr];
}

extern "C" void kernel_launch(void* const* d_in, const int* in_sizes, int n_in,
                              void* d_out, int out_size, void* d_ws, size_t ws_size,
                              hipStream_t stream) {
    const float* q  = (const float*)d_in[0];
    const float* k  = (const float*)d_in[1];
    const float* v  = (const float*)d_in[2];
    const float* Wq = (const float*)d_in[3];
    const float* bq = (const float*)d_in[4];
    const float* Wk = (const float*)d_in[5];
    const float* bk = (const float*)d_in[6];
    const float* Wv = (const float*)d_in[7];
    const float* bv = (const float*)d_in[8];
    float* out = (float*)d_out;

    const int Bb = 8, L = 2048, D = 512;
    const long long BLD = (long long)Bb * L * D;   // 8,388,608
    const long long BLL = (long long)Bb * L * L;   // 33,554,432
    const long long DD  = (long long)D * D;

    // ---- workspace layout (shorts unless noted) ----
    short* base  = (short*)d_ws;
    short* q_bf  = base;                 // BLD
    short* k_bf  = q_bf  + BLD;         // BLD
    short* v_bf  = k_bf  + BLD;         // BLD
    short* qp_bf = v_bf  + BLD;         // BLD
    short* kp_bf = qp_bf + BLD;         // BLD
    short* vp_bf = kp_bf + BLD;         // BLD
    short* vpT   = vp_bf + BLD;         // BLD
    short* Wq_bf = vpT   + BLD;         // DD
    short* Wk_bf = Wq_bf + DD;          // DD
    short* Wv_bf = Wk_bf + DD;          // DD
    short* E_bf  = Wv_bf + DD;          // BLL shorts
    float* colsum = (float*)(E_bf + BLL); // B*L floats

    dim3 blk(256);

    // 1) fused casts + colsum zero (12736 blocks)
    prep<<<dim3(12736), blk, 0, stream>>>(q, k, v, Wq, Wk, Wv,
                                          q_bf, k_bf, v_bf,
                                          Wq_bf, Wk_bf, Wv_bf, colsum);

    // 2) fused projections: M=B*L=16384, N=D=512, K=D=512, out bf16
    dim3 gproj((Bb * L) / 128, D / 128, 3);
    proj_gemm<<<gproj, blk, 0, stream>>>(q_bf, k_bf, v_bf,
                                         Wq_bf, Wk_bf, Wv_bf,
                                         bq, bk, bv,
                                         qp_bf, kp_bf, vp_bf, D, D);

    // 3) E = exp2(qp @ kp^T), colsum[b,j] = sum_i E[b,i,j]   (M=N=L, K=D)
    dim3 gS(L / 128, L / 128, Bb);
    gemm_nt_exp_colsum<<<gS, blk, 0, stream>>>(qp_bf, kp_bf, E_bf, colsum,
                                               L, D,
                                               (long long)L * D, (long long)L * D,
                                               (long long)L * L);

    // 4) vpT[d][j] = vp[j][d] / colsum[j]  per batch
    dim3 gT(D / 32, L / 32, Bb);
    transpose_scale_bf16<<<gT, blk, 0, stream>>>(vp_bf, colsum, vpT, L, D);

    // 5) out = E @ vpT^T : M=L (128-tiles), N=D (64-tiles), K=L
    dim3 gO(L / 128, D / 64, Bb);
    pv_gemm<<<gO, blk, 0, stream>>>(E_bf, vpT, out, D, L,
                                    (long long)L * L, (long long)D * L,
                                    (long long)L * D);
}

// Round 7
// 300.168 us; speedup vs baseline: 1.0471x; 1.0237x over previous
//
#include <hip/hip_runtime.h>
#include <math.h>

// B=8, L=2048, D=512, fp32 in/out. bf16 MFMA GEMMs. Column-softmax
// (axis=1 = query axis i): colsum[j]=sum_i exp(S[i,j]); j is the PV
// contraction index, so out = exp(S) @ (vp / colsum[:,None]).
// R1: qp pre-scaled by log2(e); softmax kernel uses exp2 (v_exp_f32).
// R3: LDS XOR-swizzle (col16B ^= (row>>1)&3); bank conflicts 6.3M -> 0.
// R4/R5 LESSON: prefetch variants under __syncthreads are neutral-to-worse
//     (barrier drains vmcnt(0) incl. the prefetch) -> S/pv stay at the
//     proven R3 2-barrier structure.
// R6: kill the q/k/v bf16 pre-cast round trip (144 MB HBM + ~28us kernel):
//     proj reads f32 x directly, casts during A-staging (reg-stage with
//     swizzled ds_write). prep shrinks to W-casts + colsum zero.

#define TKK 32

typedef __attribute__((ext_vector_type(8))) short bf16x8;
typedef __attribute__((ext_vector_type(4))) float floatx4;

typedef __attribute__((address_space(3))) short lds_short;
typedef const __attribute__((address_space(1))) short glob_short;

__device__ __forceinline__ short f2bf(float x) {
    unsigned u = __float_as_uint(x);
    u += 0x7fff + ((u >> 16) & 1);   // round-to-nearest-even
    return (short)(u >> 16);
}
__device__ __forceinline__ float bf2f(short s) {
    return __uint_as_float(((unsigned)(unsigned short)s) << 16);
}
__device__ __forceinline__ float exp2_fast(float x) {
    float r;
    asm("v_exp_f32 %0, %1" : "=v"(r) : "v"(x));
    return r;
}

// Stage-side swizzled column (shorts) for global_load_lds paths:
// sr = lane>>2 (row in 16-row chunk), unit = lane&3; swz = (lane>>3)&3.
#define STAGE_SC(lane) ((((lane) & 3) ^ (((lane) >> 3) & 3)) * 8)
// Read-side swizzled fragment column (shorts): logical unit h = lane>>4,
// row ≡ lane&15, s(row) = (lane>>1)&3.
#define FRAG_FC(lane) (((((lane) >> 4) ^ (((lane) >> 1) & 3))) * 8)

// ---- prep: cast W's (3*128 blocks) + zero colsum (64 blocks) ----
__global__ __launch_bounds__(256) void prep(
    const float* __restrict__ Wq, const float* __restrict__ Wk,
    const float* __restrict__ Wv,
    short* __restrict__ Wq_bf, short* __restrict__ Wk_bf, short* __restrict__ Wv_bf,
    float* __restrict__ colsum)
{
    const int b = blockIdx.x;
    if (b < 384) {
        const int z = b >> 7;
        const float* in = (z == 0) ? Wq : (z == 1) ? Wk : Wv;
        short* out = (z == 0) ? Wq_bf : (z == 1) ? Wk_bf : Wv_bf;
        const long long i = ((long long)(b & 127) * 256 + threadIdx.x) * 8;
        float4 x = *(const float4*)(in + i);
        float4 y = *(const float4*)(in + i + 4);
        bf16x8 r;
        r[0] = f2bf(x.x); r[1] = f2bf(x.y); r[2] = f2bf(x.z); r[3] = f2bf(x.w);
        r[4] = f2bf(y.x); r[5] = f2bf(y.y); r[6] = f2bf(y.z); r[7] = f2bf(y.w);
        *(bf16x8*)(out + i) = r;
    } else {
        colsum[(b - 384) * 256 + threadIdx.x] = 0.f;
    }
}

// ---- fused projections, f32-A in-flight cast (R6) ----
// C[m,n] = (sum_k x[m,k]*W[n,k] + bias[n]) * esc, out bf16.
// 128x128 tile, waves 2x2; A reg-staged from f32 with swizzled ds_write;
// B (bf16 W) via global_load_lds with pre-swizzled source.
__global__ __launch_bounds__(256) void proj_gemm(
    const float* __restrict__ x0, const float* __restrict__ x1, const float* __restrict__ x2,
    const short* __restrict__ w0, const short* __restrict__ w1, const short* __restrict__ w2,
    const float* __restrict__ b0, const float* __restrict__ b1, const float* __restrict__ b2,
    short* __restrict__ y0, short* __restrict__ y1, short* __restrict__ y2,
    int N, int K)
{
    const int z = blockIdx.z;
    const float* A    = (z == 0) ? x0 : (z == 1) ? x1 : x2;
    const short* B    = (z == 0) ? w0 : (z == 1) ? w1 : w2;
    const float* bias = (z == 0) ? b0 : (z == 1) ? b1 : b2;
    short*       C    = (z == 0) ? y0 : (z == 1) ? y1 : y2;
    const float esc   = (z == 0) ? 1.4426950408889634f : 1.0f;

    __shared__ short As[128 * TKK];
    __shared__ short Bs[128 * TKK];
    const int t    = threadIdx.x;
    const int wave = t >> 6;
    const int lane = t & 63;
    const int wm = (wave >> 1) * 64;
    const int wn = (wave & 1)  * 64;
    const int sr = lane >> 2;
    const int sc = STAGE_SC(lane);
    const int fc = FRAG_FC(lane);
    const int m0 = blockIdx.x * 128;
    const int n0 = blockIdx.y * 128;

    // A reg-stage mapping: thread t -> row ar (2 threads/row), k-half ah.
    const int ar = t >> 1;                     // 0..127
    const int ah = t & 1;                      // 16-col half of the 32-K tile
    const int aswz = (ar >> 1) & 3;            // row swizzle
    const int ap = (ah * 2) ^ aswz;            // physical 8-short unit of v0
    const float* arow = A + (long long)(m0 + ar) * K + ah * 16;

    floatx4 acc[4][4];
    #pragma unroll
    for (int i = 0; i < 4; ++i)
        #pragma unroll
        for (int j = 0; j < 4; ++j)
            acc[i][j] = (floatx4){0.f, 0.f, 0.f, 0.f};

    for (int k0 = 0; k0 < K; k0 += TKK) {
        // ---- A: load 16 f32, cast, swizzled LDS write ----
        const float4* src = (const float4*)(arow + k0);
        float4 f0 = src[0], f1 = src[1], f2_ = src[2], f3 = src[3];
        bf16x8 v0, v1;
        v0[0] = f2bf(f0.x); v0[1] = f2bf(f0.y); v0[2] = f2bf(f0.z); v0[3] = f2bf(f0.w);
        v0[4] = f2bf(f1.x); v0[5] = f2bf(f1.y); v0[6] = f2bf(f1.z); v0[7] = f2bf(f1.w);
        v1[0] = f2bf(f2_.x); v1[1] = f2bf(f2_.y); v1[2] = f2bf(f2_.z); v1[3] = f2bf(f2_.w);
        v1[4] = f2bf(f3.x); v1[5] = f2bf(f3.y); v1[6] = f2bf(f3.z); v1[7] = f2bf(f3.w);
        *(bf16x8*)&As[ar * TKK + ap * 8]       = v0;   // logical unit ah*2
        *(bf16x8*)&As[ar * TKK + (ap ^ 1) * 8] = v1;   // logical unit ah*2+1
        // ---- B: 8 chunks of 16 rows, 2 per wave (bf16 W) ----
        #pragma unroll
        for (int c = wave; c < 8; c += 4)
            __builtin_amdgcn_global_load_lds(
                (glob_short*)(B + (long long)(n0 + c * 16 + sr) * K + k0 + sc),
                (lds_short*)(Bs + c * 512), 16, 0, 0);
        __syncthreads();
        bf16x8 af[4], bfr[4];
        #pragma unroll
        for (int i = 0; i < 4; ++i)
            af[i] = *(const bf16x8*)&As[(wm + i * 16 + (lane & 15)) * TKK + fc];
        #pragma unroll
        for (int j = 0; j < 4; ++j)
            bfr[j] = *(const bf16x8*)&Bs[(wn + j * 16 + (lane & 15)) * TKK + fc];
        #pragma unroll
        for (int i = 0; i < 4; ++i)
            #pragma unroll
            for (int j = 0; j < 4; ++j)
                acc[i][j] = __builtin_amdgcn_mfma_f32_16x16x32_bf16(af[i], bfr[j], acc[i][j], 0, 0, 0);
        __syncthreads();
    }

    // Epilogue: C/D layout col=lane&15, row=(lane>>4)*4+reg (m89-verified)
    #pragma unroll
    for (int i = 0; i < 4; ++i) {
        const int rbase = m0 + wm + i * 16 + (lane >> 4) * 4;
        #pragma unroll
        for (int j = 0; j < 4; ++j) {
            const int col = n0 + wn + j * 16 + (lane & 15);
            const float bb = bias[col];
            #pragma unroll
            for (int r = 0; r < 4; ++r)
                C[(long long)(rbase + r) * N + col] = f2bf((acc[i][j][r] + bb) * esc);
        }
    }
}

// ---- PV gemm: out = E @ vpT^T ---- (exact R3 structure)
// 128x64 tile, 2 K-blocks per barrier round.
__global__ __launch_bounds__(256) void pv_gemm(
    const short* __restrict__ Eg, const short* __restrict__ vpTg,
    float* __restrict__ outg, int N, int K,
    long long sA, long long sB, long long sC)
{
    __shared__ short As[2][128 * TKK];
    __shared__ short Bs[2][64 * TKK];
    const int bz = blockIdx.z;
    const short* A = Eg   + (long long)bz * sA;
    const short* B = vpTg + (long long)bz * sB;
    float*       C = outg + (long long)bz * sC;

    const int m0 = blockIdx.x * 128;
    const int n0 = blockIdx.y * 64;
    const int t    = threadIdx.x;
    const int wave = t >> 6;
    const int lane = t & 63;
    const int wm = (wave >> 1) * 64;
    const int wn = (wave & 1)  * 32;
    const int sr = lane >> 2;
    const int sc = STAGE_SC(lane);
    const int fc = FRAG_FC(lane);

    floatx4 acc[4][2];
    #pragma unroll
    for (int i = 0; i < 4; ++i)
        #pragma unroll
        for (int j = 0; j < 2; ++j)
            acc[i][j] = (floatx4){0.f, 0.f, 0.f, 0.f};

    for (int k0 = 0; k0 < K; k0 += 2 * TKK) {
        #pragma unroll
        for (int h = 0; h < 2; ++h) {
            const int kk = k0 + h * TKK;
            #pragma unroll
            for (int c = wave; c < 8; c += 4)
                __builtin_amdgcn_global_load_lds(
                    (glob_short*)(A + (long long)(m0 + c * 16 + sr) * K + kk + sc),
                    (lds_short*)(As[h] + c * 512), 16, 0, 0);
            __builtin_amdgcn_global_load_lds(
                (glob_short*)(B + (long long)(n0 + wave * 16 + sr) * K + kk + sc),
                (lds_short*)(Bs[h] + wave * 512), 16, 0, 0);
        }
        __syncthreads();
        #pragma unroll
        for (int h = 0; h < 2; ++h) {
            bf16x8 af[4], bfr[2];
            #pragma unroll
            for (int i = 0; i < 4; ++i)
                af[i] = *(const bf16x8*)&As[h][(wm + i * 16 + (lane & 15)) * TKK + fc];
            #pragma unroll
            for (int j = 0; j < 2; ++j)
                bfr[j] = *(const bf16x8*)&Bs[h][(wn + j * 16 + (lane & 15)) * TKK + fc];
            #pragma unroll
            for (int i = 0; i < 4; ++i)
                #pragma unroll
                for (int j = 0; j < 2; ++j)
                    acc[i][j] = __builtin_amdgcn_mfma_f32_16x16x32_bf16(af[i], bfr[j], acc[i][j], 0, 0, 0);
        }
        __syncthreads();
    }

    #pragma unroll
    for (int i = 0; i < 4; ++i) {
        const int rbase = m0 + wm + i * 16 + (lane >> 4) * 4;
        #pragma unroll
        for (int j = 0; j < 2; ++j) {
            const int col = n0 + wn + j * 16 + (lane & 15);
            #pragma unroll
            for (int r = 0; r < 4; ++r)
                C[(long long)(rbase + r) * N + col] = acc[i][j][r];
        }
    }
}

// ---- NT MFMA gemm with fused exp2 + column-sum (exact R3 structure) ----
__global__ __launch_bounds__(256) void gemm_nt_exp_colsum(
    const short* __restrict__ A, const short* __restrict__ B,
    short* __restrict__ E, float* __restrict__ colsum,
    int N, int K, long long sA, long long sB, long long sE)
{
    __shared__ short As[2][128 * TKK];
    __shared__ short Bs[2][128 * TKK];
    __shared__ float wsum[4][64];
    const int bz = blockIdx.z;
    A += (long long)bz * sA;
    B += (long long)bz * sB;
    E += (long long)bz * sE;
    colsum += (long long)bz * N;

    const int m0 = blockIdx.x * 128;
    const int n0 = blockIdx.y * 128;
    const int t    = threadIdx.x;
    const int wave = t >> 6;
    const int lane = t & 63;
    const int wm = (wave >> 1) * 64;
    const int wn = (wave & 1)  * 64;
    const int sr = lane >> 2;
    const int sc = STAGE_SC(lane);
    const int fc = FRAG_FC(lane);

    floatx4 acc[4][4];
    #pragma unroll
    for (int i = 0; i < 4; ++i)
        #pragma unroll
        for (int j = 0; j < 4; ++j)
            acc[i][j] = (floatx4){0.f, 0.f, 0.f, 0.f};

    for (int k0 = 0; k0 < K; k0 += 2 * TKK) {
        #pragma unroll
        for (int h = 0; h < 2; ++h) {
            const int kk = k0 + h * TKK;
            #pragma unroll
            for (int it = 0; it < 2; ++it) {
                const int chunk = it * 4 + wave;
                const int r = chunk * 16 + sr;
                __builtin_amdgcn_global_load_lds(
                    (glob_short*)(A + (long long)(m0 + r) * K + kk + sc),
                    (lds_short*)(As[h] + chunk * 512), 16, 0, 0);
                __builtin_amdgcn_global_load_lds(
                    (glob_short*)(B + (long long)(n0 + r) * K + kk + sc),
                    (lds_short*)(Bs[h] + chunk * 512), 16, 0, 0);
            }
        }
        __syncthreads();
        #pragma unroll
        for (int h = 0; h < 2; ++h) {
            bf16x8 af[4], bfr[4];
            #pragma unroll
            for (int i = 0; i < 4; ++i)
                af[i] = *(const bf16x8*)&As[h][(wm + i * 16 + (lane & 15)) * TKK + fc];
            #pragma unroll
            for (int j = 0; j < 4; ++j)
                bfr[j] = *(const bf16x8*)&Bs[h][(wn + j * 16 + (lane & 15)) * TKK + fc];
            #pragma unroll
            for (int i = 0; i < 4; ++i)
                #pragma unroll
                for (int j = 0; j < 4; ++j)
                    acc[i][j] = __builtin_amdgcn_mfma_f32_16x16x32_bf16(af[i], bfr[j], acc[i][j], 0, 0, 0);
        }
        __syncthreads();
    }

    float csum[4] = {0.f, 0.f, 0.f, 0.f};
    #pragma unroll
    for (int i = 0; i < 4; ++i) {
        const int rbase = wm + i * 16 + (lane >> 4) * 4;
        #pragma unroll
        for (int j = 0; j < 4; ++j) {
            const int col = wn + j * 16 + (lane & 15);
            #pragma unroll
            for (int r = 0; r < 4; ++r) {
                const float e = exp2_fast(acc[i][j][r]);
                E[(long long)(m0 + rbase + r) * N + (n0 + col)] = f2bf(e);
                csum[j] += e;
            }
        }
    }
    #pragma unroll
    for (int j = 0; j < 4; ++j) {
        csum[j] += __shfl_xor(csum[j], 16);
        csum[j] += __shfl_xor(csum[j], 32);
    }
    if (lane < 16) {
        #pragma unroll
        for (int j = 0; j < 4; ++j)
            wsum[wave][j * 16 + lane] = csum[j];
    }
    __syncthreads();
    if (t < 128) {
        const float s = (t < 64) ? (wsum[0][t] + wsum[2][t])
                                 : (wsum[1][t - 64] + wsum[3][t - 64]);
        atomicAdd(&colsum[n0 + t], s);
    }
}

// ---- bf16 transpose + per-row scale: out[c][r] = in[r][c] / colsum[r] ----
__global__ __launch_bounds__(256) void transpose_scale_bf16(
    const short* __restrict__ in, const float* __restrict__ colsum,
    short* __restrict__ out, int R, int Cc)
{
    __shared__ short tile[32][33];
    const int b = blockIdx.z;
    in  += (long long)b * R * Cc;
    out += (long long)b * R * Cc;
    colsum += (long long)b * R;
    const int c0 = blockIdx.x * 32, r0 = blockIdx.y * 32;
    const int tx = threadIdx.x & 31, ty = threadIdx.x >> 5;
    #pragma unroll
    for (int rr = ty; rr < 32; rr += 8) {
        const float rs = 1.f / colsum[r0 + rr];
        tile[rr][tx] = f2bf(bf2f(in[(long long)(r0 + rr) * Cc + c0 + tx]) * rs);
    }
    __syncthreads();
    #pragma unroll
    for (int rr = ty; rr < 32; rr += 8)
        out[(long long)(c0 + rr) * R + r0 + tx] = tile[tx][rr];
}

extern "C" void kernel_launch(void* const* d_in, const int* in_sizes, int n_in,
                              void* d_out, int out_size, void* d_ws, size_t ws_size,
                              hipStream_t stream) {
    const float* q  = (const float*)d_in[0];
    const float* k  = (const float*)d_in[1];
    const float* v  = (const float*)d_in[2];
    const float* Wq = (const float*)d_in[3];
    const float* bq = (const float*)d_in[4];
    const float* Wk = (const float*)d_in[5];
    const float* bk = (const float*)d_in[6];
    const float* Wv = (const float*)d_in[7];
    const float* bv = (const float*)d_in[8];
    float* out = (float*)d_out;

    const int Bb = 8, L = 2048, D = 512;
    const long long BLD = (long long)Bb * L * D;   // 8,388,608
    const long long BLL = (long long)Bb * L * L;   // 33,554,432
    const long long DD  = (long long)D * D;

    // ---- workspace layout (shorts unless noted) ----
    short* base  = (short*)d_ws;
    short* qp_bf = base;                 // BLD
    short* kp_bf = qp_bf + BLD;         // BLD
    short* vp_bf = kp_bf + BLD;         // BLD
    short* vpT   = vp_bf + BLD;         // BLD
    short* Wq_bf = vpT   + BLD;         // DD
    short* Wk_bf = Wq_bf + DD;          // DD
    short* Wv_bf = Wk_bf + DD;          // DD
    short* E_bf  = Wv_bf + DD;          // BLL shorts
    float* colsum = (float*)(E_bf + BLL); // B*L floats

    dim3 blk(256);

    // 1) W casts + colsum zero (448 blocks)
    prep<<<dim3(448), blk, 0, stream>>>(Wq, Wk, Wv, Wq_bf, Wk_bf, Wv_bf, colsum);

    // 2) fused projections from f32 inputs: M=B*L=16384, N=D=512, K=D=512
    dim3 gproj((Bb * L) / 128, D / 128, 3);
    proj_gemm<<<gproj, blk, 0, stream>>>(q, k, v,
                                         Wq_bf, Wk_bf, Wv_bf,
                                         bq, bk, bv,
                                         qp_bf, kp_bf, vp_bf, D, D);

    // 3) E = exp2(qp @ kp^T), colsum[b,j] = sum_i E[b,i,j]   (M=N=L, K=D)
    dim3 gS(L / 128, L / 128, Bb);
    gemm_nt_exp_colsum<<<gS, blk, 0, stream>>>(qp_bf, kp_bf, E_bf, colsum,
                                               L, D,
                                               (long long)L * D, (long long)L * D,
                                               (long long)L * L);

    // 4) vpT[d][j] = vp[j][d] / colsum[j]  per batch
    dim3 gT(D / 32, L / 32, Bb);
    transpose_scale_bf16<<<gT, blk, 0, stream>>>(vp_bf, colsum, vpT, L, D);

    // 5) out = E @ vpT^T : M=L (128-tiles), N=D (64-tiles), K=L
    dim3 gO(L / 128, D / 64, Bb);
    pv_gemm<<<gO, blk, 0, stream>>>(E_bf, vpT, out, D, L,
                                    (long long)L * L, (long long)D * L,
                                    (long long)L * D);
}